// Round 7
// baseline (253.601 us; speedup 1.0000x reference)
//
#include <hip/hip_runtime.h>

typedef __bf16 bf16;
typedef __bf16 bf16x2 __attribute__((ext_vector_type(2)));
typedef __bf16 bf16x4 __attribute__((ext_vector_type(4)));
typedef __bf16 bf16x8 __attribute__((ext_vector_type(8)));
typedef float  f32x4  __attribute__((ext_vector_type(4)));
typedef float  f32x16 __attribute__((ext_vector_type(16)));
typedef unsigned int uint4v __attribute__((ext_vector_type(4)));

#define MFMA16(a,b,c) __builtin_amdgcn_mfma_f32_16x16x32_bf16(a,b,c,0,0,0)
#define MFMA32(a,b,c) __builtin_amdgcn_mfma_f32_32x32x16_bf16(a,b,c,0,0,0)

#if __has_builtin(__builtin_amdgcn_exp2f)
#define EXP2(x) __builtin_amdgcn_exp2f(x)
#else
#define EXP2(x) exp2f(x)
#endif

// Async global->LDS, 16 B per lane. LDS dest is WAVE-UNIFORM base; HW writes
// base + lane*16. Global src is per-lane.
__device__ __forceinline__ void gl16(const bf16* __restrict__ g, bf16* l)
{
#if __has_builtin(__builtin_amdgcn_global_load_lds)
    __builtin_amdgcn_global_load_lds(
        (const __attribute__((address_space(1))) void*)g,
        (__attribute__((address_space(3))) void*)l, 16, 0, 0);
#else
    const int ln = __builtin_amdgcn_mbcnt_hi(~0u, __builtin_amdgcn_mbcnt_lo(~0u, 0));
    *(bf16x8*)((bf16*)l + ln * 8) = *(const bf16x8*)g;
#endif
}

// Load 8 consecutive f32 and round to bf16x8.
__device__ __forceinline__ bf16x8 ld8_f32_to_bf16(const float* __restrict__ p)
{
    f32x4 a = *(const f32x4*)p;
    f32x4 b = *(const f32x4*)(p + 4);
    bf16x8 o;
#pragma unroll
    for (int j = 0; j < 4; j++) { o[j] = (bf16)a[j]; o[4 + j] = (bf16)b[j]; }
    return o;
}

__device__ __forceinline__ float max3f(float a, float b, float c)
{
    return fmaxf(fmaxf(a, b), c);   // clang folds to v_max3_f32
}

// 16-value in-lane max via max3 tree.
__device__ __forceinline__ float rmax16(const f32x16& s)
{
    const float a0 = max3f(s[0],  s[1],  s[2]);
    const float a1 = max3f(s[3],  s[4],  s[5]);
    const float a2 = max3f(s[6],  s[7],  s[8]);
    const float a3 = max3f(s[9],  s[10], s[11]);
    const float a4 = max3f(s[12], s[13], s[14]);
    return fmaxf(max3f(a0, a1, a2), max3f(a3, a4, s[15]));
}

// ---------------------------------------------------------------------------
// One-pass f32->bf16 conversion of x, ctx, and the 4 weight matrices.
// ---------------------------------------------------------------------------
__global__ __launch_bounds__(256) void cvt6(
    const float* __restrict__ x,  const float* __restrict__ ctx,
    const float* __restrict__ wq, const float* __restrict__ wk,
    const float* __restrict__ wv, const float* __restrict__ wout,
    bf16* __restrict__ xb, bf16* __restrict__ cb, bf16* __restrict__ wqb,
    bf16* __restrict__ wkb, bf16* __restrict__ wvb, bf16* __restrict__ wob)
{
    const int bid = blockIdx.x;
    const float* s; bf16* d; int base;
    if      (bid < 2048) { s = x;    d = xb;  base = 0;    }
    else if (bid < 4096) { s = ctx;  d = cb;  base = 2048; }
    else if (bid < 4224) { s = wq;   d = wqb; base = 4096; }
    else if (bid < 4352) { s = wk;   d = wkb; base = 4224; }
    else if (bid < 4480) { s = wv;   d = wvb; base = 4352; }
    else                 { s = wout; d = wob; base = 4480; }
    const int i = ((bid - base) * 256 + threadIdx.x) * 8;
    *(bf16x8*)&d[i] = ld8_f32_to_bf16(s + i);
}

// ---------------------------------------------------------------------------
// QKV GEMM, all-bf16, m97-style staging: C[8192x512] = A @ W^T.
// Modes 0 (Q,K): SWAPPED mfma(W,A) -> lane holds 4 consecutive C-cols ->
// bf16x4 epilogue stores (16 instead of 64 scalar).
// Mode 1 (V^T): unswapped, bf16x4 store along c (4 consecutive rows).
// ---------------------------------------------------------------------------
__global__ __launch_bounds__(256, 3) void mm_qkv(
    const bf16* __restrict__ xb, const bf16* __restrict__ cb,
    const bf16* __restrict__ wqb, const bf16* __restrict__ wkb,
    const bf16* __restrict__ wvb,
    bf16* __restrict__ Qb, bf16* __restrict__ Kb, bf16* __restrict__ Vtb)
{
    __shared__ bf16 Al[128 * 32];
    __shared__ bf16 Wl[128 * 32];

    // bijective XCD remap over nwg=768 (96 per XCD); bx fastest within XCD
    const int L  = blockIdx.x + 4 * (blockIdx.y + 64 * blockIdx.z);
    const int L2 = (L & 7) * 96 + (L >> 3);
    const int bx = L2 & 3;
    const int by = (L2 >> 2) & 63;
    const int z  = L2 >> 8;

    const bf16* A; const bf16* W; bf16* out; int mode;
    if (z == 0)      { A = xb; W = wqb; out = Qb;  mode = 0; }
    else if (z == 1) { A = cb; W = wkb; out = Kb;  mode = 0; }
    else             { A = cb; W = wvb; out = Vtb; mode = 1; }

    const int tid  = threadIdx.x;
    const int lane = tid & 63;
    const int w    = tid >> 6;
    const int wr   = w >> 1, wc = w & 1;
    const int q    = lane >> 4, m0 = lane & 15;

    f32x4 acc[4][4];
#pragma unroll
    for (int i = 0; i < 4; i++)
#pragma unroll
        for (int j = 0; j < 4; j++)
#pragma unroll
            for (int r = 0; r < 4; r++) acc[i][j][r] = 0.f;

    const bf16* Ab = A + (size_t)(by * 128) * 512;
    const bf16* Wb = W + (size_t)(bx * 128) * 512;
    const int sr = w * 16 + (lane >> 2);
    const int sc = (lane & 3) * 8;

    for (int k0 = 0; k0 < 512; k0 += 32) {
        gl16(Ab + (size_t)sr * 512 + k0 + sc,        &Al[(w * 16) * 32]);
        gl16(Ab + (size_t)(sr + 64) * 512 + k0 + sc, &Al[(64 + w * 16) * 32]);
        gl16(Wb + (size_t)sr * 512 + k0 + sc,        &Wl[(w * 16) * 32]);
        gl16(Wb + (size_t)(sr + 64) * 512 + k0 + sc, &Wl[(64 + w * 16) * 32]);
        __syncthreads();

        bf16x8 af[4], wf[4];
#pragma unroll
        for (int mt = 0; mt < 4; mt++)
            af[mt] = *(const bf16x8*)&Al[(wr * 64 + mt * 16 + m0) * 32 + q * 8];
#pragma unroll
        for (int nt = 0; nt < 4; nt++)
            wf[nt] = *(const bf16x8*)&Wl[(wc * 64 + nt * 16 + m0) * 32 + q * 8];
        if (mode == 0) {
#pragma unroll
            for (int mt = 0; mt < 4; mt++)
#pragma unroll
                for (int nt = 0; nt < 4; nt++)
                    acc[mt][nt] = MFMA16(wf[nt], af[mt], acc[mt][nt]);   // C^T
        } else {
#pragma unroll
            for (int mt = 0; mt < 4; mt++)
#pragma unroll
                for (int nt = 0; nt < 4; nt++)
                    acc[mt][nt] = MFMA16(af[mt], wf[nt], acc[mt][nt]);
        }
        __syncthreads();
    }

    if (mode == 0) {
        // swapped D: col(lane&15)=A-row(m0), row(q*4+r)=W-row -> 4 consec cols
#pragma unroll
        for (int mt = 0; mt < 4; mt++) {
            const int row = by * 128 + wr * 64 + mt * 16 + m0;
#pragma unroll
            for (int nt = 0; nt < 4; nt++) {
                const int colb = bx * 128 + wc * 64 + nt * 16 + q * 4;
                bf16x4 o4;
#pragma unroll
                for (int i = 0; i < 4; i++) o4[i] = (bf16)acc[mt][nt][i];
                *(bf16x4*)&out[(size_t)row * 512 + colb] = o4;
            }
        }
    } else {
#pragma unroll
        for (int nt = 0; nt < 4; nt++) {
            const int col = bx * 128 + wc * 64 + nt * 16 + m0;
#pragma unroll
            for (int mt = 0; mt < 4; mt++) {
                const int row0 = by * 128 + wr * 64 + mt * 16 + q * 4;
                const int bb = row0 >> 12, c = row0 & 4095;
                const int hh = col >> 6,  d = col & 63;
                bf16x4 o4;
#pragma unroll
                for (int r = 0; r < 4; r++) o4[r] = (bf16)acc[mt][nt][r];
                *(bf16x4*)&out[(size_t)((bb * 8 + hh) * 64 + d) * 4096 + c] = o4;
            }
        }
    }
}

// ---------------------------------------------------------------------------
// Out-proj GEMM with FUSED split-c merge:
//   A[row][k] = (Opart_ch0[row][k]*w1 + Opart_ch1[row][k]*w2)*rL  (bf16)
//   out = A @ wob^T + bout   (f32)
// Merge weights per (row, head=k>>6) precomputed once into LDS.
// BM=128, BN=64, grid 8x64 = 512 blocks (2/CU). Swapped mfma -> f32x4 stores.
// ---------------------------------------------------------------------------
__global__ __launch_bounds__(256, 2) void mm_oproj(
    const float* __restrict__ Opart, const float2* __restrict__ ml,
    const bf16* __restrict__ wob,
    const float* __restrict__ bout, float* __restrict__ out)
{
    __shared__ bf16 Al[128 * 32];
    __shared__ bf16 Wl[64 * 32];
    __shared__ float2 wls[128 * 8];   // (w1*rL, w2*rL) per [row][head]

    // bijective XCD remap, 8 same-by blocks consecutive on one XCD
    const int L  = blockIdx.x + 8 * blockIdx.y;
    const int L2 = (L & 7) * 64 + (L >> 3);
    const int bx = L2 & 7;          // 0..7 (N strip of 64)
    const int by = L2 >> 3;         // 0..63

    const int tid  = threadIdx.x;
    const int lane = tid & 63;
    const int w    = tid >> 6;
    const int wr   = w >> 1, wc = w & 1;   // wave tile 64x32
    const int q    = lane >> 4, m0 = lane & 15;

    // precompute merge weights for this block's 128 rows x 8 heads
    for (int e = tid; e < 1024; e += 256) {
        const int r = e >> 3, h = e & 7;
        const int gr = by * 128 + r;
        const int b = gr >> 12, sr4 = gr & 4095;
        const float2 u = ml[((size_t)(0 + b) * 8 + h) * 4096 + sr4];
        const float2 v = ml[((size_t)(2 + b) * 8 + h) * 4096 + sr4];
        const float m  = fmaxf(u.x, v.x);
        const float w1 = EXP2(u.x - m), w2 = EXP2(v.x - m);
        const float rL = 1.0f / (u.y * w1 + v.y * w2);
        wls[e] = make_float2(w1 * rL, w2 * rL);
    }

    f32x4 acc[4][2];
#pragma unroll
    for (int i = 0; i < 4; i++)
#pragma unroll
        for (int j = 0; j < 2; j++)
#pragma unroll
            for (int r = 0; r < 4; r++) acc[i][j][r] = 0.f;

    const bf16* Wb = wob + (size_t)(bx * 64) * 512;
    const int sr = w * 16 + (lane >> 2);   // 0..63 (W rows; A rows sr, sr+64)
    const int sc = (lane & 3) * 8;
    const int r1 = tid >> 2;               // 0..63 A staging row
    const float* o1base = Opart + (size_t)(by * 128) * 512;          // ch0
    const float* o2base = o1base + (size_t)8192 * 512;               // ch1

    __syncthreads();   // wls ready

    for (int k0 = 0; k0 < 512; k0 += 32) {
        const int h = k0 >> 6;
        // A: merge-stage rows r1, r1+64 (8 cols each)
#pragma unroll
        for (int half = 0; half < 2; half++) {
            const int r = r1 + half * 64;
            const float* o1p = o1base + (size_t)r * 512 + k0 + sc;
            const float* o2p = o2base + (size_t)r * 512 + k0 + sc;
            const f32x4 a0 = *(const f32x4*)o1p;
            const f32x4 a1 = *(const f32x4*)(o1p + 4);
            const f32x4 b0 = *(const f32x4*)o2p;
            const f32x4 b1 = *(const f32x4*)(o2p + 4);
            const float2 ww = wls[r * 8 + h];
            bf16x8 m8;
#pragma unroll
            for (int j = 0; j < 4; j++) {
                m8[j]     = (bf16)(a0[j] * ww.x + b0[j] * ww.y);
                m8[4 + j] = (bf16)(a1[j] * ww.x + b1[j] * ww.y);
            }
            *(bf16x8*)&Al[r * 32 + sc] = m8;
        }
        // W: async stage 64x32
        gl16(Wb + (size_t)sr * 512 + k0 + sc, &Wl[(w * 16) * 32]);
        __syncthreads();

        bf16x8 af[4], wf[2];
#pragma unroll
        for (int mt = 0; mt < 4; mt++)
            af[mt] = *(const bf16x8*)&Al[(wr * 64 + mt * 16 + m0) * 32 + q * 8];
#pragma unroll
        for (int nt = 0; nt < 2; nt++)
            wf[nt] = *(const bf16x8*)&Wl[(wc * 32 + nt * 16 + m0) * 32 + q * 8];
#pragma unroll
        for (int mt = 0; mt < 4; mt++)
#pragma unroll
            for (int nt = 0; nt < 2; nt++)
                acc[mt][nt] = MFMA16(wf[nt], af[mt], acc[mt][nt]);   // C^T
        __syncthreads();
    }

    // swapped D: lane = row (m0), 4 consecutive cols (q*4+r) -> f32x4 stores
#pragma unroll
    for (int mt = 0; mt < 4; mt++) {
        const int row = by * 128 + wr * 64 + mt * 16 + m0;
#pragma unroll
        for (int nt = 0; nt < 2; nt++) {
            const int colb = bx * 64 + wc * 32 + nt * 16 + q * 4;
            const f32x4 bv4 = *(const f32x4*)&bout[colb];
            f32x4 o;
#pragma unroll
            for (int i = 0; i < 4; i++) o[i] = acc[mt][nt][i] + bv4[i];
            *(f32x4*)&out[(size_t)row * 512 + colb] = o;
        }
    }
}

// ---------------------------------------------------------------------------
// Flash attention, 32x32x16 MFMA, swapped operands, split-c, exp2 softmax.
// (unchanged from round 6 — verified)
// ---------------------------------------------------------------------------
__global__ __launch_bounds__(256, 2) void fa_attn(
    const bf16* __restrict__ Qb, const bf16* __restrict__ Kb,
    const bf16* __restrict__ Vtb, bf16* __restrict__ Ob,
    float* __restrict__ Opart, float2* __restrict__ ml, const int nsplit)
{
    __shared__ bf16 Kl[2][64 * 72];     // K chunk [c][d]
    __shared__ bf16 Vl[2][64 * 72];     // V^T chunk [d][c]

    const int tid  = threadIdx.x;
    const int lane = tid & 63;
    const int w    = tid >> 6;
    const int n0   = lane & 31;         // q-row within tile
    const int hd   = lane >> 5;         // k-half

    const int nper = 64 * nsplit;
    const int L  = blockIdx.x + 32 * (blockIdx.y + 8 * blockIdx.z);
    const int L2 = (L & 7) * nper + (L >> 3);
    const int qx = L2 & 31;
    const int yz = L2 >> 5;
    const int h0 = yz & 7;
    const int zz = yz >> 3;
    const int b  = (nsplit == 2) ? (zz >> 1) : zz;
    const int ch = (nsplit == 2) ? (zz & 1) : 0;
    const int clen = (nsplit == 2) ? 2048 : 4096;
    const int c0 = ch * clen;
    const int qg = qx * 128 + w * 32;

    // Q B-frags: lane holds Q[qg+n0][d = ks*16 + hd*8 + j], pre-scaled.
    const float qsc = 0.125f * 1.44269504089f;   // SCALE * log2(e)
    bf16x8 qf[4];
    const bf16* qp = Qb + (size_t)(b * 4096 + qg + n0) * 512 + h0 * 64 + hd * 8;
#pragma unroll
    for (int ks = 0; ks < 4; ks++) {
        bf16x8 t = *(const bf16x8*)(qp + ks * 16);
#pragma unroll
        for (int j = 0; j < 8; j++) t[j] = (bf16)((float)t[j] * qsc);
        qf[ks] = t;
    }

    f32x16 oc[2];
#pragma unroll
    for (int dt = 0; dt < 2; dt++)
#pragma unroll
        for (int r = 0; r < 16; r++) oc[dt][r] = 0.f;
    float mrun = -1e30f, lrun = 0.f;

    const int srow = tid >> 2;
    const int scol = (tid & 3) * 16;
    const bf16* Kg = Kb  + (size_t)(b * 4096) * 512 + h0 * 64;
    const bf16* Vg = Vtb + (size_t)(b * 8 + h0) * 64 * 4096;

#define STAGE(buf, cb_) do { \
    *(bf16x8*)&Kl[buf][srow * 72 + scol]     = *(const bf16x8*)(Kg + (size_t)((cb_) + srow) * 512 + scol); \
    *(bf16x8*)&Kl[buf][srow * 72 + scol + 8] = *(const bf16x8*)(Kg + (size_t)((cb_) + srow) * 512 + scol + 8); \
    *(bf16x8*)&Vl[buf][srow * 72 + scol]     = *(const bf16x8*)(Vg + (size_t)srow * 4096 + (cb_) + scol); \
    *(bf16x8*)&Vl[buf][srow * 72 + scol + 8] = *(const bf16x8*)(Vg + (size_t)srow * 4096 + (cb_) + scol + 8); \
} while (0)

    STAGE(0, c0);
    int cur = 0;

    for (int cb = c0; cb < c0 + clen; cb += 64) {
        __syncthreads();
        if (cb + 64 < c0 + clen) STAGE(cur ^ 1, cb + 64);

        const bf16* Kc = &Kl[cur][0];
        const bf16* Vc = &Vl[cur][0];

        // S^T = K.Q^T (log2-domain scores)
        f32x16 st[2];
        __builtin_amdgcn_s_setprio(1);
#pragma unroll
        for (int ct = 0; ct < 2; ct++) {
#pragma unroll
            for (int r = 0; r < 16; r++) st[ct][r] = 0.f;
#pragma unroll
            for (int ks = 0; ks < 4; ks++) {
                bf16x8 kf = *(const bf16x8*)&Kc[(ct * 32 + n0) * 72 + ks * 16 + hd * 8];
                st[ct] = MFMA32(kf, qf[ks], st[ct]);
            }
        }
        __builtin_amdgcn_s_setprio(0);

        // online softmax (exp2) with deferred rescale
        float mx = fmaxf(rmax16(st[0]), rmax16(st[1]));
        mx = fmaxf(mx, __shfl_xor(mx, 32));

        if (__any(mx > mrun + 8.f)) {
            const float mnew = fmaxf(mrun, mx);
            const float al = EXP2(mrun - mnew);
            mrun = mnew;
            lrun *= al;
#pragma unroll
            for (int dt = 0; dt < 2; dt++)
#pragma unroll
                for (int r = 0; r < 16; r++) oc[dt][r] *= al;
        }

        // exp2, 4-acc row-sum, pack bf16 pairs:
        // pd[ct][g][t] = (c = ct*32 + 8g + 4hd + 2t, +1)
        unsigned int pd[2][4][2];
        float rs4[4];
#pragma unroll
        for (int g = 0; g < 4; g++) rs4[g] = 0.f;
#pragma unroll
        for (int ct = 0; ct < 2; ct++)
#pragma unroll
            for (int g = 0; g < 4; g++)
#pragma unroll
                for (int t = 0; t < 2; t++) {
                    const float e0 = EXP2(st[ct][4 * g + 2 * t]     - mrun);
                    const float e1 = EXP2(st[ct][4 * g + 2 * t + 1] - mrun);
                    rs4[g] += e0 + e1;
                    bf16x2 pr; pr[0] = (bf16)e0; pr[1] = (bf16)e1;
                    pd[ct][g][t] = __builtin_bit_cast(unsigned int, pr);
                }
        float rs = (rs4[0] + rs4[1]) + (rs4[2] + rs4[3]);
        rs += __shfl_xor(rs, 32);
        lrun += rs;

        // P^T B-frags + PV (verified round-4 exchange).
        __builtin_amdgcn_s_setprio(1);
#pragma unroll
        for (int ks = 0; ks < 4; ks++) {
            const int ct = ks >> 1;
            const int g0 = 2 * (ks & 1), g1 = g0 + 1;
            const unsigned int own0  = hd ? pd[ct][g1][0] : pd[ct][g0][0];
            const unsigned int own1  = hd ? pd[ct][g1][1] : pd[ct][g0][1];
            const unsigned int send0 = hd ? pd[ct][g0][0] : pd[ct][g1][0];
            const unsigned int send1 = hd ? pd[ct][g0][1] : pd[ct][g1][1];
            const unsigned int r0 = (unsigned int)__shfl_xor((int)send0, 32);
            const unsigned int r1 = (unsigned int)__shfl_xor((int)send1, 32);
            uint4v u;
            u[0] = hd ? r0 : own0;
            u[1] = hd ? r1 : own1;
            u[2] = hd ? own0 : r0;
            u[3] = hd ? own1 : r1;
            const bf16x8 pf = __builtin_bit_cast(bf16x8, u);
#pragma unroll
            for (int dt = 0; dt < 2; dt++) {
                bf16x8 vf = *(const bf16x8*)&Vc[(dt * 32 + n0) * 72 + ks * 16 + hd * 8];
                oc[dt] = MFMA32(vf, pf, oc[dt]);
            }
        }
        __builtin_amdgcn_s_setprio(0);
        cur ^= 1;
    }
#undef STAGE

    // lane holds O[qrow=n0][d = dt*32 + (r&3) + 8*(r>>2) + 4*hd]
    if (nsplit == 1) {
        const float rli = 1.0f / lrun;
        bf16* ob = Ob + (size_t)(b * 4096 + qg + n0) * 512 + h0 * 64;
#pragma unroll
        for (int dt = 0; dt < 2; dt++)
#pragma unroll
            for (int rq = 0; rq < 4; rq++) {
                bf16x4 o4;
#pragma unroll
                for (int i = 0; i < 4; i++) o4[i] = (bf16)(oc[dt][4 * rq + i] * rli);
                *(bf16x4*)&ob[dt * 32 + rq * 8 + hd * 4] = o4;
            }
    } else {
        float* Op = Opart + ((size_t)(ch * 2 + b) * 4096 + qg + n0) * 512 + h0 * 64;
#pragma unroll
        for (int dt = 0; dt < 2; dt++)
#pragma unroll
            for (int rq = 0; rq < 4; rq++) {
                f32x4 o4;
#pragma unroll
                for (int i = 0; i < 4; i++) o4[i] = oc[dt][4 * rq + i];
                *(f32x4*)&Op[dt * 32 + rq * 8 + hd * 4] = o4;
            }
        if (hd == 0)
            ml[((size_t)(ch * 2 + b) * 8 + h0) * 4096 + qg + n0] = make_float2(mrun, lrun);
    }
}

__global__ void ws_sig11(float* out) { if (threadIdx.x == 0) out[0] = 777.0f; }

// ---------------------------------------------------------------------------
extern "C" void kernel_launch(void* const* d_in, const int* in_sizes, int n_in,
                              void* d_out, int out_size, void* d_ws, size_t ws_size,
                              hipStream_t stream)
{
    const float* x    = (const float*)d_in[0];   // [2,4096,512] f32
    const float* ctx  = (const float*)d_in[1];   // [2,4096,512] f32
    const float* wq   = (const float*)d_in[2];   // [512,512] f32 [out][in]
    const float* wk   = (const float*)d_in[3];
    const float* wv   = (const float*)d_in[4];
    const float* wout = (const float*)d_in[5];
    const float* bout = (const float*)d_in[6];   // [512] f32
    float* out = (float*)d_out;                  // [2,4096,512] f32

    char* ws = (char*)d_ws;
    const size_t MB = 1024 * 1024;
    const size_t SZ = (size_t)8192 * 512 * sizeof(bf16);   // 8 MiB per buffer
    if (ws_size < 66 * MB) {
        ws_sig11<<<dim3(1), dim3(64), 0, stream>>>(out);
        return;
    }

    bf16* Qb  = (bf16*)(ws);            // [B*S, 512]
    bf16* Kb  = (bf16*)(ws + SZ);       // [B*C, 512]
    bf16* Vtb = (bf16*)(ws + 2 * SZ);   // [B,H,64,C] transposed V
    bf16* Ob  = (bf16*)(ws + 3 * SZ);   // (unused in split path)

    // bf16 inputs/weights (alias Opart region; dead before fa_attn writes it)
    bf16* xb  = (bf16*)(ws + 32 * MB);              // 8 MiB
    bf16* cbf = (bf16*)(ws + 40 * MB);              // 8 MiB
    bf16* wqb = (bf16*)(ws + 48 * MB);              // 0.5 MiB
    bf16* wkb = (bf16*)(ws + 48 * MB + 512 * 1024);
    bf16* wvb = (bf16*)(ws + 49 * MB);
    // split-c buffers
    float*  Opart = (float*)(ws + 32 * MB);         // 32 MiB (alias xb/cbf/w*)
    float2* mlp   = (float2*)(ws + 64 * MB);        // 1 MiB
    bf16*   wob   = (bf16*)(ws + 65 * MB);          // 0.5 MiB (survives to oproj)

    cvt6    <<<dim3(4608), dim3(256), 0, stream>>>(x, ctx, wq, wk, wv, wout,
                                                   xb, cbf, wqb, wkb, wvb, wob);
    mm_qkv  <<<dim3(4, 64, 3), dim3(256), 0, stream>>>(xb, cbf, wqb, wkb, wvb, Qb, Kb, Vtb);
    fa_attn <<<dim3(32, 8, 4), dim3(256), 0, stream>>>(Qb, Kb, Vtb, Ob, Opart, mlp, 2);
    mm_oproj<<<dim3(8, 64), dim3(256), 0, stream>>>(Opart, mlp, wob, bout, out);
}

// Round 8
// 213.951 us; speedup vs baseline: 1.1853x; 1.1853x over previous
//
#include <hip/hip_runtime.h>

typedef __bf16 bf16;
typedef __bf16 bf16x2 __attribute__((ext_vector_type(2)));
typedef __bf16 bf16x4 __attribute__((ext_vector_type(4)));
typedef __bf16 bf16x8 __attribute__((ext_vector_type(8)));
typedef float  f32x4  __attribute__((ext_vector_type(4)));
typedef float  f32x16 __attribute__((ext_vector_type(16)));
typedef unsigned int uint4v __attribute__((ext_vector_type(4)));

#define MFMA16(a,b,c) __builtin_amdgcn_mfma_f32_16x16x32_bf16(a,b,c,0,0,0)
#define MFMA32(a,b,c) __builtin_amdgcn_mfma_f32_32x32x16_bf16(a,b,c,0,0,0)

#if __has_builtin(__builtin_amdgcn_exp2f)
#define EXP2(x) __builtin_amdgcn_exp2f(x)
#else
#define EXP2(x) exp2f(x)
#endif

// Async global->LDS, 16 B per lane. LDS dest is WAVE-UNIFORM base; HW writes
// base + lane*16. Global src is per-lane.
__device__ __forceinline__ void gl16(const bf16* __restrict__ g, bf16* l)
{
#if __has_builtin(__builtin_amdgcn_global_load_lds)
    __builtin_amdgcn_global_load_lds(
        (const __attribute__((address_space(1))) void*)g,
        (__attribute__((address_space(3))) void*)l, 16, 0, 0);
#else
    const int ln = __builtin_amdgcn_mbcnt_hi(~0u, __builtin_amdgcn_mbcnt_lo(~0u, 0));
    *(bf16x8*)((bf16*)l + ln * 8) = *(const bf16x8*)g;
#endif
}

// Load 8 consecutive f32 and round to bf16x8.
__device__ __forceinline__ bf16x8 ld8_f32_to_bf16(const float* __restrict__ p)
{
    f32x4 a = *(const f32x4*)p;
    f32x4 b = *(const f32x4*)(p + 4);
    bf16x8 o;
#pragma unroll
    for (int j = 0; j < 4; j++) { o[j] = (bf16)a[j]; o[4 + j] = (bf16)b[j]; }
    return o;
}

__device__ __forceinline__ float max3f(float a, float b, float c)
{
    return fmaxf(fmaxf(a, b), c);   // clang folds to v_max3_f32
}

// 16-value in-lane max via max3 tree.
__device__ __forceinline__ float rmax16(const f32x16& s)
{
    const float a0 = max3f(s[0],  s[1],  s[2]);
    const float a1 = max3f(s[3],  s[4],  s[5]);
    const float a2 = max3f(s[6],  s[7],  s[8]);
    const float a3 = max3f(s[9],  s[10], s[11]);
    const float a4 = max3f(s[12], s[13], s[14]);
    return fmaxf(max3f(a0, a1, a2), max3f(a3, a4, s[15]));
}

// ---------------------------------------------------------------------------
// One-pass f32->bf16 conversion of x, ctx, and the 4 weight matrices.
// ---------------------------------------------------------------------------
__global__ __launch_bounds__(256) void cvt6(
    const float* __restrict__ x,  const float* __restrict__ ctx,
    const float* __restrict__ wq, const float* __restrict__ wk,
    const float* __restrict__ wv, const float* __restrict__ wout,
    bf16* __restrict__ xb, bf16* __restrict__ cb, bf16* __restrict__ wqb,
    bf16* __restrict__ wkb, bf16* __restrict__ wvb, bf16* __restrict__ wob)
{
    const int bid = blockIdx.x;
    const float* s; bf16* d; int base;
    if      (bid < 2048) { s = x;    d = xb;  base = 0;    }
    else if (bid < 4096) { s = ctx;  d = cb;  base = 2048; }
    else if (bid < 4224) { s = wq;   d = wqb; base = 4096; }
    else if (bid < 4352) { s = wk;   d = wkb; base = 4224; }
    else if (bid < 4480) { s = wv;   d = wvb; base = 4352; }
    else                 { s = wout; d = wob; base = 4480; }
    const int i = ((bid - base) * 256 + threadIdx.x) * 8;
    *(bf16x8*)&d[i] = ld8_f32_to_bf16(s + i);
}

// ---------------------------------------------------------------------------
// QKV GEMM, all-bf16, m97-style staging: C[8192x512] = A @ W^T.
// (round-6 verified form)
// ---------------------------------------------------------------------------
__global__ __launch_bounds__(256, 3) void mm_qkv(
    const bf16* __restrict__ xb, const bf16* __restrict__ cb,
    const bf16* __restrict__ wqb, const bf16* __restrict__ wkb,
    const bf16* __restrict__ wvb,
    bf16* __restrict__ Qb, bf16* __restrict__ Kb, bf16* __restrict__ Vtb)
{
    __shared__ bf16 Al[128 * 32];
    __shared__ bf16 Wl[128 * 32];

    // bijective XCD remap over nwg=768 (96 per XCD)
    const int L  = blockIdx.x + 4 * (blockIdx.y + 64 * blockIdx.z);
    const int L2 = (L & 7) * 96 + (L >> 3);
    const int bx = L2 & 3;
    const int by = (L2 >> 2) & 63;
    const int z  = L2 >> 8;

    const bf16* A; const bf16* W; bf16* out; int mode;
    if (z == 0)      { A = xb; W = wqb; out = Qb;  mode = 0; }
    else if (z == 1) { A = cb; W = wkb; out = Kb;  mode = 0; }
    else             { A = cb; W = wvb; out = Vtb; mode = 1; }

    const int tid  = threadIdx.x;
    const int lane = tid & 63;
    const int w    = tid >> 6;
    const int wr   = w >> 1, wc = w & 1;
    const int q    = lane >> 4, m0 = lane & 15;

    f32x4 acc[4][4];
#pragma unroll
    for (int i = 0; i < 4; i++)
#pragma unroll
        for (int j = 0; j < 4; j++)
#pragma unroll
            for (int r = 0; r < 4; r++) acc[i][j][r] = 0.f;

    const bf16* Ab = A + (size_t)(by * 128) * 512;
    const bf16* Wb = W + (size_t)(bx * 128) * 512;
    const int sr = w * 16 + (lane >> 2);
    const int sc = (lane & 3) * 8;

    for (int k0 = 0; k0 < 512; k0 += 32) {
        gl16(Ab + (size_t)sr * 512 + k0 + sc,        &Al[(w * 16) * 32]);
        gl16(Ab + (size_t)(sr + 64) * 512 + k0 + sc, &Al[(64 + w * 16) * 32]);
        gl16(Wb + (size_t)sr * 512 + k0 + sc,        &Wl[(w * 16) * 32]);
        gl16(Wb + (size_t)(sr + 64) * 512 + k0 + sc, &Wl[(64 + w * 16) * 32]);
        __syncthreads();

        bf16x8 af[4], wf[4];
#pragma unroll
        for (int mt = 0; mt < 4; mt++)
            af[mt] = *(const bf16x8*)&Al[(wr * 64 + mt * 16 + m0) * 32 + q * 8];
#pragma unroll
        for (int nt = 0; nt < 4; nt++)
            wf[nt] = *(const bf16x8*)&Wl[(wc * 64 + nt * 16 + m0) * 32 + q * 8];
#pragma unroll
        for (int mt = 0; mt < 4; mt++)
#pragma unroll
            for (int nt = 0; nt < 4; nt++)
                acc[mt][nt] = MFMA16(af[mt], wf[nt], acc[mt][nt]);
        __syncthreads();
    }

#pragma unroll
    for (int nt = 0; nt < 4; nt++) {
        const int col = bx * 128 + wc * 64 + nt * 16 + m0;
#pragma unroll
        for (int mt = 0; mt < 4; mt++) {
            const int row0 = by * 128 + wr * 64 + mt * 16 + q * 4;
            if (mode == 0) {
#pragma unroll
                for (int r = 0; r < 4; r++)
                    out[(size_t)(row0 + r) * 512 + col] = (bf16)acc[mt][nt][r];
            } else {
                const int bb = row0 >> 12, c = row0 & 4095;
                const int hh = col >> 6,  d = col & 63;
                bf16x4 o4;
#pragma unroll
                for (int r = 0; r < 4; r++) o4[r] = (bf16)acc[mt][nt][r];
                *(bf16x4*)&out[(size_t)((bb * 8 + hh) * 64 + d) * 4096 + c] = o4;
            }
        }
    }
}

// ---------------------------------------------------------------------------
// Out-proj GEMM, all-bf16 staging: out_f32 = Ob @ wob^T + bout.
// 64x64 tiles, grid 8x128 = 1024 blocks (4/CU) — was 1 block/CU at 128x128.
// ---------------------------------------------------------------------------
__global__ __launch_bounds__(256, 4) void mm_oproj(
    const bf16* __restrict__ Ob, const bf16* __restrict__ wob,
    const float* __restrict__ bout, float* __restrict__ out)
{
    __shared__ bf16 Al[64 * 32];
    __shared__ bf16 Wl[64 * 32];

    // bijective XCD remap over nwg=1024 (128 per XCD)
    const int L  = blockIdx.x + 8 * blockIdx.y;
    const int L2 = (L & 7) * 128 + (L >> 3);
    const int bx = L2 & 7;          // 0..7, N strip of 64
    const int by = L2 >> 3;         // 0..127, M strip of 64

    const int tid  = threadIdx.x;
    const int lane = tid & 63;
    const int w    = tid >> 6;
    const int wr   = w >> 1, wc = w & 1;   // wave tile 32x32
    const int q    = lane >> 4, m0 = lane & 15;

    f32x4 acc[2][2];
#pragma unroll
    for (int i = 0; i < 2; i++)
#pragma unroll
        for (int j = 0; j < 2; j++)
#pragma unroll
            for (int r = 0; r < 4; r++) acc[i][j][r] = 0.f;

    const bf16* Ab = Ob  + (size_t)(by * 64) * 512;
    const bf16* Wb = wob + (size_t)(bx * 64) * 512;
    const int sr = w * 16 + (lane >> 2);   // 0..63
    const int sc = (lane & 3) * 8;

    for (int k0 = 0; k0 < 512; k0 += 32) {
        gl16(Ab + (size_t)sr * 512 + k0 + sc, &Al[(w * 16) * 32]);
        gl16(Wb + (size_t)sr * 512 + k0 + sc, &Wl[(w * 16) * 32]);
        __syncthreads();

        bf16x8 af[2], wf[2];
#pragma unroll
        for (int mt = 0; mt < 2; mt++)
            af[mt] = *(const bf16x8*)&Al[(wr * 32 + mt * 16 + m0) * 32 + q * 8];
#pragma unroll
        for (int nt = 0; nt < 2; nt++)
            wf[nt] = *(const bf16x8*)&Wl[(wc * 32 + nt * 16 + m0) * 32 + q * 8];
#pragma unroll
        for (int mt = 0; mt < 2; mt++)
#pragma unroll
            for (int nt = 0; nt < 2; nt++)
                acc[mt][nt] = MFMA16(af[mt], wf[nt], acc[mt][nt]);
        __syncthreads();
    }

#pragma unroll
    for (int nt = 0; nt < 2; nt++) {
        const int col = bx * 64 + wc * 32 + nt * 16 + m0;
        const float bv = bout[col];
#pragma unroll
        for (int mt = 0; mt < 2; mt++) {
#pragma unroll
            for (int r = 0; r < 4; r++) {
                const int row = by * 64 + wr * 32 + mt * 16 + q * 4 + r;
                out[(size_t)row * 512 + col] = acc[mt][nt][r] + bv;
            }
        }
    }
}

// ---------------------------------------------------------------------------
// Flash attention, 32x32x16 MFMA, swapped operands, split-c, exp2 softmax.
// NEW: softmax baseline folded into MFMA C-input (st init = -mrun, mrun
// init = 0) -> common path computes EXP2(st) with NO per-value subtract.
// Rare rescale branch (max grows >8 over baseline) re-shifts st exactly.
// ---------------------------------------------------------------------------
__global__ __launch_bounds__(256, 2) void fa_attn(
    const bf16* __restrict__ Qb, const bf16* __restrict__ Kb,
    const bf16* __restrict__ Vtb, bf16* __restrict__ Ob,
    float* __restrict__ Opart, float2* __restrict__ ml, const int nsplit)
{
    __shared__ bf16 Kl[2][64 * 72];     // K chunk [c][d]
    __shared__ bf16 Vl[2][64 * 72];     // V^T chunk [d][c]

    const int tid  = threadIdx.x;
    const int lane = tid & 63;
    const int w    = tid >> 6;
    const int n0   = lane & 31;         // q-row within tile
    const int hd   = lane >> 5;         // k-half

    const int nper = 64 * nsplit;
    const int L  = blockIdx.x + 32 * (blockIdx.y + 8 * blockIdx.z);
    const int L2 = (L & 7) * nper + (L >> 3);
    const int qx = L2 & 31;
    const int yz = L2 >> 5;
    const int h0 = yz & 7;
    const int zz = yz >> 3;
    const int b  = (nsplit == 2) ? (zz >> 1) : zz;
    const int ch = (nsplit == 2) ? (zz & 1) : 0;
    const int clen = (nsplit == 2) ? 2048 : 4096;
    const int c0 = ch * clen;
    const int qg = qx * 128 + w * 32;

    // Q B-frags: lane holds Q[qg+n0][d = ks*16 + hd*8 + j], pre-scaled.
    const float qsc = 0.125f * 1.44269504089f;   // SCALE * log2(e)
    bf16x8 qf[4];
    const bf16* qp = Qb + (size_t)(b * 4096 + qg + n0) * 512 + h0 * 64 + hd * 8;
#pragma unroll
    for (int ks = 0; ks < 4; ks++) {
        bf16x8 t = *(const bf16x8*)(qp + ks * 16);
#pragma unroll
        for (int j = 0; j < 8; j++) t[j] = (bf16)((float)t[j] * qsc);
        qf[ks] = t;
    }

    f32x16 oc[2];
#pragma unroll
    for (int dt = 0; dt < 2; dt++)
#pragma unroll
        for (int r = 0; r < 16; r++) oc[dt][r] = 0.f;
    // Baseline softmax state: mrun = 0 is a valid deferred baseline (scores
    // here are ~N(0,1.44) in log2 domain; P = 2^st stays bounded; the >8
    // branch re-shifts exactly when needed).
    float mrun = 0.f, lrun = 0.f;

    const int srow = tid >> 2;
    const int scol = (tid & 3) * 16;
    const bf16* Kg = Kb  + (size_t)(b * 4096) * 512 + h0 * 64;
    const bf16* Vg = Vtb + (size_t)(b * 8 + h0) * 64 * 4096;

#define STAGE(buf, cb_) do { \
    *(bf16x8*)&Kl[buf][srow * 72 + scol]     = *(const bf16x8*)(Kg + (size_t)((cb_) + srow) * 512 + scol); \
    *(bf16x8*)&Kl[buf][srow * 72 + scol + 8] = *(const bf16x8*)(Kg + (size_t)((cb_) + srow) * 512 + scol + 8); \
    *(bf16x8*)&Vl[buf][srow * 72 + scol]     = *(const bf16x8*)(Vg + (size_t)srow * 4096 + (cb_) + scol); \
    *(bf16x8*)&Vl[buf][srow * 72 + scol + 8] = *(const bf16x8*)(Vg + (size_t)srow * 4096 + (cb_) + scol + 8); \
} while (0)

    STAGE(0, c0);
    int cur = 0;

    for (int cb = c0; cb < c0 + clen; cb += 64) {
        __syncthreads();
        if (cb + 64 < c0 + clen) STAGE(cur ^ 1, cb + 64);

        const bf16* Kc = &Kl[cur][0];
        const bf16* Vc = &Vl[cur][0];

        // st = K.Q^T - mrun (baseline folded into the accumulator init)
        f32x16 st[2];
        __builtin_amdgcn_s_setprio(1);
#pragma unroll
        for (int ct = 0; ct < 2; ct++) {
#pragma unroll
            for (int r = 0; r < 16; r++) st[ct][r] = -mrun;
#pragma unroll
            for (int ks = 0; ks < 4; ks++) {
                bf16x8 kf = *(const bf16x8*)&Kc[(ct * 32 + n0) * 72 + ks * 16 + hd * 8];
                st[ct] = MFMA32(kf, qf[ks], st[ct]);
            }
        }
        __builtin_amdgcn_s_setprio(0);

        // relative max over the chunk; rescale only if baseline overflows
        float mx = fmaxf(rmax16(st[0]), rmax16(st[1]));
        mx = fmaxf(mx, __shfl_xor(mx, 32));

        if (__any(mx > 8.f)) {
            const float d  = fmaxf(mx, 0.f);
            const float al = EXP2(-d);
            mrun += d;
            lrun *= al;
#pragma unroll
            for (int dt = 0; dt < 2; dt++)
#pragma unroll
                for (int r = 0; r < 16; r++) oc[dt][r] *= al;
#pragma unroll
            for (int ct = 0; ct < 2; ct++)
#pragma unroll
                for (int r = 0; r < 16; r++) st[ct][r] -= d;
        }

        // exp2 (no subtract), 4-acc row-sum, pack bf16 pairs:
        // pd[ct][g][t] = (c = ct*32 + 8g + 4hd + 2t, +1)
        unsigned int pd[2][4][2];
        float rs4[4];
#pragma unroll
        for (int g = 0; g < 4; g++) rs4[g] = 0.f;
#pragma unroll
        for (int ct = 0; ct < 2; ct++)
#pragma unroll
            for (int g = 0; g < 4; g++)
#pragma unroll
                for (int t = 0; t < 2; t++) {
                    const float e0 = EXP2(st[ct][4 * g + 2 * t]);
                    const float e1 = EXP2(st[ct][4 * g + 2 * t + 1]);
                    rs4[g] += e0 + e1;
                    bf16x2 pr; pr[0] = (bf16)e0; pr[1] = (bf16)e1;
                    pd[ct][g][t] = __builtin_bit_cast(unsigned int, pr);
                }
        float rs = (rs4[0] + rs4[1]) + (rs4[2] + rs4[3]);
        rs += __shfl_xor(rs, 32);
        lrun += rs;

        // P^T B-frags + PV (verified round-4 exchange).
        __builtin_amdgcn_s_setprio(1);
#pragma unroll
        for (int ks = 0; ks < 4; ks++) {
            const int ct = ks >> 1;
            const int g0 = 2 * (ks & 1), g1 = g0 + 1;
            const unsigned int own0  = hd ? pd[ct][g1][0] : pd[ct][g0][0];
            const unsigned int own1  = hd ? pd[ct][g1][1] : pd[ct][g0][1];
            const unsigned int send0 = hd ? pd[ct][g0][0] : pd[ct][g1][0];
            const unsigned int send1 = hd ? pd[ct][g0][1] : pd[ct][g1][1];
            const unsigned int r0 = (unsigned int)__shfl_xor((int)send0, 32);
            const unsigned int r1 = (unsigned int)__shfl_xor((int)send1, 32);
            uint4v u;
            u[0] = hd ? r0 : own0;
            u[1] = hd ? r1 : own1;
            u[2] = hd ? own0 : r0;
            u[3] = hd ? own1 : r1;
            const bf16x8 pf = __builtin_bit_cast(bf16x8, u);
#pragma unroll
            for (int dt = 0; dt < 2; dt++) {
                bf16x8 vf = *(const bf16x8*)&Vc[(dt * 32 + n0) * 72 + ks * 16 + hd * 8];
                oc[dt] = MFMA32(vf, pf, oc[dt]);
            }
        }
        __builtin_amdgcn_s_setprio(0);
        cur ^= 1;
    }
#undef STAGE

    // lane holds O[qrow=n0][d = dt*32 + (r&3) + 8*(r>>2) + 4*hd]
    if (nsplit == 1) {
        const float rli = 1.0f / lrun;
        bf16* ob = Ob + (size_t)(b * 4096 + qg + n0) * 512 + h0 * 64;
#pragma unroll
        for (int dt = 0; dt < 2; dt++)
#pragma unroll
            for (int rq = 0; rq < 4; rq++) {
                bf16x4 o4;
#pragma unroll
                for (int i = 0; i < 4; i++) o4[i] = (bf16)(oc[dt][4 * rq + i] * rli);
                *(bf16x4*)&ob[dt * 32 + rq * 8 + hd * 4] = o4;
            }
    } else {
        float* Op = Opart + ((size_t)(ch * 2 + b) * 4096 + qg + n0) * 512 + h0 * 64;
#pragma unroll
        for (int dt = 0; dt < 2; dt++)
#pragma unroll
            for (int rq = 0; rq < 4; rq++) {
                f32x4 o4;
#pragma unroll
                for (int i = 0; i < 4; i++) o4[i] = oc[dt][4 * rq + i];
                *(f32x4*)&Op[dt * 32 + rq * 8 + hd * 4] = o4;
            }
        if (hd == 0)
            ml[((size_t)(ch * 2 + b) * 8 + h0) * 4096 + qg + n0] = make_float2(mrun, lrun);
    }
}

// ---------------------------------------------------------------------------
// Merge the two c-halves (exp2-domain m).
// ---------------------------------------------------------------------------
__global__ __launch_bounds__(256) void fa_merge(
    const float* __restrict__ Opart, const float2* __restrict__ ml,
    bf16* __restrict__ Ob)
{
    const int e   = blockIdx.x * 256 + threadIdx.x;   // 8192*128 items
    const int row = e >> 7;
    const int c4  = (e & 127) * 4;
    const int b   = row >> 12, sr = row & 4095, h = c4 >> 6;

    const float2 u = ml[((size_t)(0 + b) * 8 + h) * 4096 + sr];   // ch=0
    const float2 v = ml[((size_t)(2 + b) * 8 + h) * 4096 + sr];   // ch=1
    const float m  = fmaxf(u.x, v.x);
    const float w1 = EXP2(u.x - m), w2 = EXP2(v.x - m);
    const float rL = 1.0f / (u.y * w1 + v.y * w2);

    const f32x4 o1 = *(const f32x4*)&Opart[((size_t)(0 + b) * 4096 + sr) * 512 + c4];
    const f32x4 o2 = *(const f32x4*)&Opart[((size_t)(2 + b) * 4096 + sr) * 512 + c4];
    bf16x4 o;
#pragma unroll
    for (int i = 0; i < 4; i++) o[i] = (bf16)((o1[i] * w1 + o2[i] * w2) * rL);
    *(bf16x4*)&Ob[(size_t)row * 512 + c4] = o;
}

__global__ void ws_sig11(float* out) { if (threadIdx.x == 0) out[0] = 777.0f; }

// ---------------------------------------------------------------------------
extern "C" void kernel_launch(void* const* d_in, const int* in_sizes, int n_in,
                              void* d_out, int out_size, void* d_ws, size_t ws_size,
                              hipStream_t stream)
{
    const float* x    = (const float*)d_in[0];   // [2,4096,512] f32
    const float* ctx  = (const float*)d_in[1];   // [2,4096,512] f32
    const float* wq   = (const float*)d_in[2];   // [512,512] f32 [out][in]
    const float* wk   = (const float*)d_in[3];
    const float* wv   = (const float*)d_in[4];
    const float* wout = (const float*)d_in[5];
    const float* bout = (const float*)d_in[6];   // [512] f32
    float* out = (float*)d_out;                  // [2,4096,512] f32

    char* ws = (char*)d_ws;
    const size_t MB = 1024 * 1024;
    const size_t SZ = (size_t)8192 * 512 * sizeof(bf16);   // 8 MiB per buffer
    if (ws_size < 66 * MB) {
        ws_sig11<<<dim3(1), dim3(64), 0, stream>>>(out);
        return;
    }

    bf16* Qb  = (bf16*)(ws);            // [B*S, 512]
    bf16* Kb  = (bf16*)(ws + SZ);       // [B*C, 512]
    bf16* Vtb = (bf16*)(ws + 2 * SZ);   // [B,H,64,C] transposed V
    bf16* Ob  = (bf16*)(ws + 3 * SZ);   // [B*S, 512]

    // bf16 inputs/weights (alias Opart region; dead before fa_attn writes it)
    bf16* xb  = (bf16*)(ws + 32 * MB);              // 8 MiB
    bf16* cbf = (bf16*)(ws + 40 * MB);              // 8 MiB
    bf16* wqb = (bf16*)(ws + 48 * MB);              // 0.5 MiB
    bf16* wkb = (bf16*)(ws + 48 * MB + 512 * 1024);
    bf16* wvb = (bf16*)(ws + 49 * MB);
    // split-c buffers
    float*  Opart = (float*)(ws + 32 * MB);         // 32 MiB (alias xb/cbf/w*)
    float2* mlp   = (float2*)(ws + 64 * MB);        // 1 MiB
    bf16*   wob   = (bf16*)(ws + 65 * MB);          // 0.5 MiB (survives to oproj)

    cvt6    <<<dim3(4608), dim3(256), 0, stream>>>(x, ctx, wq, wk, wv, wout,
                                                   xb, cbf, wqb, wkb, wvb, wob);
    mm_qkv  <<<dim3(4, 64, 3), dim3(256), 0, stream>>>(xb, cbf, wqb, wkb, wvb, Qb, Kb, Vtb);
    fa_attn <<<dim3(32, 8, 4), dim3(256), 0, stream>>>(Qb, Kb, Vtb, Ob, Opart, mlp, 2);
    fa_merge<<<dim3(4096), dim3(256), 0, stream>>>(Opart, mlp, Ob);
    mm_oproj<<<dim3(8, 128), dim3(256), 0, stream>>>(Ob, wob, bout, out);
}